// Round 8
// baseline (175.258 us; speedup 1.0000x reference)
//
#include <hip/hip_runtime.h>
#include <hip/hip_bf16.h>
#include <cstdint>
#include <cstddef>

// ---------------------------------------------------------------------------
// Biaffine: out[b,x,y,o] = sum_ij in1[b,x,i] w1[i,o,j] in2[b,y,j] + lin terms
// B=32 S=1024 D=256 O=2.
//   prep2: in2 -> bf16, lin2+bias, w1 transpose  (in1 handled by gemm1)
//   gemm1: stages in1 fp32->bf16 in-kernel, computes lin1, T = in1 @ w1t^T
//   gemm2: out = T . in2b + lin.  R4 regime: __syncthreads ring, 2 blocks/CU
//          (TLP covers store drains), BK=128 (16 steps, half the barriers),
//          lin staged in LDS (no global loads in the loop/epilogue).
// ---------------------------------------------------------------------------

typedef __bf16 bf16_t;
typedef __bf16 bf16x4 __attribute__((ext_vector_type(4)));
typedef __bf16 bf16x8 __attribute__((ext_vector_type(8)));
typedef float  f32x4  __attribute__((ext_vector_type(4)));
typedef float  f32x16 __attribute__((ext_vector_type(16)));

#define NB   32
#define NS   1024
#define ND   256
#define NM   (NB * NS)
#define NN1  512

__device__ __forceinline__ void gload_lds16(const void* g, void* l) {
  __builtin_amdgcn_global_load_lds(
      (__attribute__((address_space(1))) void*)g,
      (__attribute__((address_space(3))) void*)l, 16, 0, 0);
}

// ---------------------------------------------------------------------------
// prep2: in2 cast + lin2(+bias) + w1 transpose
// ---------------------------------------------------------------------------
__global__ __launch_bounds__(256) void prep2_kernel(
    const float* __restrict__ in2, const float* __restrict__ w1,
    const float* __restrict__ w2,
    bf16_t* __restrict__ in2b, bf16_t* __restrict__ w1t,
    float* __restrict__ lin)
{
  int bid = blockIdx.x;
  if (bid < 8192) {
    int wave = threadIdx.x >> 6;
    int lane = threadIdx.x & 63;
    int r = bid * 4 + wave;               // in2 row 0..32767

    float4 v = *(const float4*)(in2 + (size_t)r * ND + lane * 4);
    bf16x4 h;
    h[0] = (bf16_t)v.x; h[1] = (bf16_t)v.y; h[2] = (bf16_t)v.z; h[3] = (bf16_t)v.w;
    *(bf16x4*)(in2b + (size_t)r * ND + lane * 4) = h;

    int dbase = ND + lane * 4;
    float a0 = v.x * w2[(dbase + 0) * 2 + 0] + v.y * w2[(dbase + 1) * 2 + 0]
             + v.z * w2[(dbase + 2) * 2 + 0] + v.w * w2[(dbase + 3) * 2 + 0];
    float a1 = v.x * w2[(dbase + 0) * 2 + 1] + v.y * w2[(dbase + 1) * 2 + 1]
             + v.z * w2[(dbase + 2) * 2 + 1] + v.w * w2[(dbase + 3) * 2 + 1];
    #pragma unroll
    for (int off = 32; off > 0; off >>= 1) {
      a0 += __shfl_down(a0, off, 64);
      a1 += __shfl_down(a1, off, 64);
    }
    if (lane == 0) {
      a0 += w2[2 * ND * 2 + 0]; a1 += w2[2 * ND * 2 + 1];   // bias folded in
      lin[(size_t)(NM + r) * 2 + 0] = a0;
      lin[(size_t)(NM + r) * 2 + 1] = a1;
    }
  } else {
    int wb = bid - 8192;                  // 0..63
    int t  = threadIdx.x;
    #pragma unroll
    for (int e = 0; e < 8; ++e) {
      int q  = wb * 2048 + e * 256 + t;
      int oj = q >> 8;
      int i  = q & 255;
      w1t[q] = (bf16_t)w1[i * NN1 + oj];
    }
  }
}

// ---------------------------------------------------------------------------
// gemm1: T[m,oj] = in1[m,:] . w1t[oj,:]  (in1 read as fp32, cast in-kernel)
// Also computes lin1 (fp32, from L2-hot rows). BM=64, 48 KB LDS, 3 blocks/CU.
// ---------------------------------------------------------------------------
__global__ __launch_bounds__(256, 3) void gemm1_kernel(
    const float* __restrict__ in1, const bf16_t* __restrict__ Bt,
    const float* __restrict__ w2,
    bf16_t* __restrict__ T, float* __restrict__ lin)
{
  __shared__ __align__(16) bf16_t Ap[64 * 256];      // 32 KB, swizzled
  __shared__ __align__(16) bf16_t Bc[2][128 * 32];   // 2 x 8 KB

  int m0 = blockIdx.x * 64;
  int t = threadIdx.x, lane = t & 63, wid = t >> 6;
  int wm = (wid >> 1) * 32, wn = (wid & 1) * 64;

  // reg-stage A: fp32 -> bf16 -> LDS (swizzled: LDS linear, source k-slot ^row&7)
  #pragma unroll
  for (int i = 0; i < 8; ++i) {
    int unit = i * 256 + t;
    int row = unit >> 5;
    int c   = unit & 31;
    int cs  = c ^ (row & 7);
    const float* src = in1 + (size_t)(m0 + row) * ND + cs * 8;
    float4 v0 = *(const float4*)(src);
    float4 v1 = *(const float4*)(src + 4);
    bf16x8 h;
    h[0] = (bf16_t)v0.x; h[1] = (bf16_t)v0.y; h[2] = (bf16_t)v0.z; h[3] = (bf16_t)v0.w;
    h[4] = (bf16_t)v1.x; h[5] = (bf16_t)v1.y; h[6] = (bf16_t)v1.z; h[7] = (bf16_t)v1.w;
    *(bf16x8*)&Ap[(size_t)unit * 8] = h;
  }
  // stage B chunk 0
  #pragma unroll
  for (int i = 0; i < 2; ++i) {
    int unit = i * 256 + t;
    int row = unit >> 2, c = unit & 3, cs = c ^ (row & 3);
    gload_lds16(Bt + (size_t)row * ND + cs * 8, (char*)Bc[0] + unit * 16);
  }
  // lin1 for this block's 64 rows (L2-hot re-read; one-shot)
  {
    float wc0[4], wc1[4];
    #pragma unroll
    for (int k = 0; k < 4; ++k) {
      wc0[k] = w2[(lane * 4 + k) * 2 + 0];
      wc1[k] = w2[(lane * 4 + k) * 2 + 1];
    }
    for (int rr = 0; rr < 16; ++rr) {
      int row = m0 + wid * 16 + rr;
      float4 v = *(const float4*)(in1 + (size_t)row * ND + lane * 4);
      float a0 = v.x * wc0[0] + v.y * wc0[1] + v.z * wc0[2] + v.w * wc0[3];
      float a1 = v.x * wc1[0] + v.y * wc1[1] + v.z * wc1[2] + v.w * wc1[3];
      #pragma unroll
      for (int off = 32; off > 0; off >>= 1) {
        a0 += __shfl_down(a0, off, 64);
        a1 += __shfl_down(a1, off, 64);
      }
      if (lane == 0) {
        lin[(size_t)row * 2 + 0] = a0;
        lin[(size_t)row * 2 + 1] = a1;
      }
    }
  }
  __syncthreads();

  f32x4 acc[2][4] = {};

  for (int s = 0; s < 32; ++s) {
    if (s + 1 < 32) {
      int nt = (s + 1) >> 3, j0 = ((s + 1) & 7) * 32;
      bf16_t* dst = (bf16_t*)Bc[(s + 1) & 1];
      #pragma unroll
      for (int i = 0; i < 2; ++i) {
        int unit = i * 256 + t;
        int row = unit >> 2, c = unit & 3, cs = c ^ (row & 3);
        gload_lds16(Bt + (size_t)(nt * 128 + row) * ND + j0 + cs * 8,
                    (char*)dst + unit * 16);
      }
    }
    const bf16_t* Bcur = Bc[s & 1];
    bf16x8 bfr[4];
    #pragma unroll
    for (int ni = 0; ni < 4; ++ni) {
      int r = wn + ni * 16 + (lane & 15);
      int cp = (lane >> 4) ^ (r & 3);
      bfr[ni] = *(const bf16x8*)&Bcur[r * 32 + cp * 8];
    }
    #pragma unroll
    for (int mi = 0; mi < 2; ++mi) {
      int r = wm + mi * 16 + (lane & 15);
      int cl = (s & 7) * 4 + (lane >> 4);
      int cp = cl ^ (r & 7);
      bf16x8 af = *(const bf16x8*)&Ap[r * 256 + cp * 8];
      #pragma unroll
      for (int ni = 0; ni < 4; ++ni)
        acc[mi][ni] = __builtin_amdgcn_mfma_f32_16x16x32_bf16(
            af, bfr[ni], acc[mi][ni], 0, 0, 0);
    }
    if ((s & 7) == 7) {
      int nt = s >> 3;
      #pragma unroll
      for (int mi = 0; mi < 2; ++mi) {
        int row = m0 + wm + mi * 16 + ((lane >> 4) << 2);
        #pragma unroll
        for (int ni = 0; ni < 4; ++ni) {
          int col = nt * 128 + wn + ni * 16 + (lane & 15);
          #pragma unroll
          for (int r_ = 0; r_ < 4; ++r_)
            T[(size_t)(row + r_) * NN1 + col] = (bf16_t)acc[mi][ni][r_];
          acc[mi][ni] = (f32x4){0.f, 0.f, 0.f, 0.f};
        }
      }
    }
    __syncthreads();
  }
}

// ---------------------------------------------------------------------------
// gemm2: per (b, 64-row x-tile). A in registers (af[2][16], 128 VGPR/wave).
// B: 16 chunks (8 y-tiles x 2 kc of 128k = 32 KB) through a 2-slot ring in
// the 64 KB LDS union. Per step: issue next chunk -> 32 MFMA (32x32x16) ->
// (odd step) epilogue from LDS-staged lin + 32 float2 stores -> __syncthreads.
// 2 blocks/CU: sibling block keeps HBM stores flowing during our drains.
// ---------------------------------------------------------------------------
__global__ __launch_bounds__(256, 2) void gemm2_kernel(
    const bf16_t* __restrict__ Tm, const bf16_t* __restrict__ in2b,
    const float* __restrict__ lin, float* __restrict__ out)
{
  // 64 KB ring (union with one-shot A staging) + 512 B lin1 + 8 KB lin2
  __shared__ __align__(16) char smem[65536 + 512 + 8192];

  // XCD-aware bijective swizzle: 512 blocks, 64/XCD -> 4 batches per XCD
  int blk = (blockIdx.x & 7) * 64 + (blockIdx.x >> 3);
  int b   = blk >> 4;
  int x0  = (blk & 15) * 64;
  const bf16_t* Tb = Tm   + (size_t)b * NS * NN1;
  const bf16_t* Ib = in2b + (size_t)b * NS * ND;

  int t = threadIdx.x, lane = t & 63, wid = t >> 6;
  int wx = (wid >> 1) * 32;        // x-slot: 0 or 32
  int wy = (wid & 1) * 64;         // y-slot within 128-wide y-tile: 0 or 64
  int l31 = lane & 31, lhi = lane >> 5;

  // ---- stage A-panel 64x512 (swizzled) into smem[0..64K) ----
  bf16_t* Apan = (bf16_t*)smem;
  #pragma unroll
  for (int i = 0; i < 16; ++i) {
    int unit = i * 256 + t;
    int row = unit >> 6;           // 64 slots/row
    int c   = unit & 63;
    int cs  = c ^ (row & 7);
    gload_lds16(Tb + (size_t)(x0 + row) * NN1 + cs * 8, (char*)Apan + unit * 16);
  }
  // ---- stage lin into LDS (epilogue then has zero global loads) ----
  if (t < 32)
    gload_lds16(lin + ((size_t)b * NS + x0) * 2 + t * 4, smem + 65536 + t * 16);
  #pragma unroll
  for (int i = 0; i < 2; ++i) {
    int u = i * 256 + t;
    gload_lds16(lin + ((size_t)NM + (size_t)b * NS) * 2 + u * 4,
                smem + 66048 + u * 16);
  }
  __syncthreads();

  // ---- prefill A-frags: af[o][ks] (32 bf16x8 = 128 VGPR) ----
  bf16x8 af[2][16];
  {
    int row = wx + l31;
    #pragma unroll
    for (int o = 0; o < 2; ++o)
      #pragma unroll
      for (int ks = 0; ks < 16; ++ks) {
        int ls = o * 32 + ks * 2 + lhi;
        int sm = ls ^ (row & 7);
        af[o][ks] = *(const bf16x8*)&Apan[(row * 64 + sm) * 8];
      }
  }
  __syncthreads();   // Apan dead; ring may overwrite

  // ---- stage chunk 0 (y-tile 0, k 0..127) into slot 0: 2048 units ----
  #pragma unroll
  for (int i = 0; i < 8; ++i) {
    int u = i * 256 + t;
    int row = u >> 4, sl = u & 15;
    int cs = sl ^ (row & 7);
    gload_lds16(Ib + (size_t)row * ND + cs * 8, smem + u * 16);
  }
  __syncthreads();

  f32x16 acc[2][2] = {};   // [ni][o]
  float2* outb = (float2*)(out + (size_t)b * NS * NS * 2);
  const float2* l1s = (const float2*)(smem + 65536);
  const float2* l2s = (const float2*)(smem + 66048);
  int lrow_base = wx + 4 * lhi;

  // issue chunk (YI2 y-tile, KB2 k-half) into ring slot SLOT2
#define G2_ISSUE(YI2, KB2, SLOT2) do {                                        \
    char* dst_ = smem + (SLOT2) * 32768;                                      \
    _Pragma("unroll")                                                         \
    for (int i_ = 0; i_ < 8; ++i_) {                                          \
      int u_ = i_ * 256 + t;                                                  \
      int row_ = u_ >> 4, sl_ = u_ & 15;                                      \
      int cs_ = sl_ ^ (row_ & 7);                                             \
      gload_lds16(Ib + (size_t)((YI2) * 128 + row_) * ND + (KB2) + cs_ * 8,   \
                  dst_ + u_ * 16);                                            \
    }                                                                         \
  } while (0)

  // step: compute chunk (G, PAR) from slot PAR; PAR literal -> af static
#define G2_STEP(G, PAR, DO_ISSUE, NYI, NKB, NSLOT) do {                       \
    if (DO_ISSUE) G2_ISSUE(NYI, NKB, NSLOT);                                  \
    const bf16_t* Bp_ = (const bf16_t*)(smem + (PAR) * 32768);                \
    _Pragma("unroll")                                                         \
    for (int ni_ = 0; ni_ < 2; ++ni_) {                                       \
      int row_ = wy + ni_ * 32 + l31;                                         \
      _Pragma("unroll")                                                       \
      for (int ks_ = 0; ks_ < 8; ++ks_) {                                     \
        int sm_ = (ks_ * 2 + lhi) ^ (row_ & 7);                               \
        bf16x8 bfv_ = *(const bf16x8*)&Bp_[(row_ * 16 + sm_) * 8];            \
        acc[ni_][0] = __builtin_amdgcn_mfma_f32_32x32x16_bf16(                \
            af[0][(PAR) * 8 + ks_], bfv_, acc[ni_][0], 0, 0, 0);              \
        acc[ni_][1] = __builtin_amdgcn_mfma_f32_32x32x16_bf16(                \
            af[1][(PAR) * 8 + ks_], bfv_, acc[ni_][1], 0, 0, 0);              \
      }                                                                       \
    }                                                                         \
    if (PAR == 1) {                                                           \
      int y0_ = (G) * 128;                                                    \
      float2 l2v_[2];                                                         \
      _Pragma("unroll")                                                       \
      for (int ni_ = 0; ni_ < 2; ++ni_)                                       \
        l2v_[ni_] = l2s[y0_ + wy + ni_ * 32 + l31];                           \
      _Pragma("unroll")                                                       \
      for (int r_ = 0; r_ < 16; ++r_) {                                       \
        int lrow_ = lrow_base + (r_ & 3) + 8 * (r_ >> 2);                     \
        float2 l1v_ = l1s[lrow_];                                             \
        _Pragma("unroll")                                                     \
        for (int ni_ = 0; ni_ < 2; ++ni_) {                                   \
          int col_ = y0_ + wy + ni_ * 32 + l31;                               \
          float2 v_;                                                          \
          v_.x = acc[ni_][0][r_] + l1v_.x + l2v_[ni_].x;                      \
          v_.y = acc[ni_][1][r_] + l1v_.y + l2v_[ni_].y;                      \
          outb[(size_t)(x0 + lrow_) * NS + col_] = v_;                        \
        }                                                                     \
      }                                                                       \
      acc[0][0] = (f32x16)(0.f); acc[0][1] = (f32x16)(0.f);                   \
      acc[1][0] = (f32x16)(0.f); acc[1][1] = (f32x16)(0.f);                   \
    }                                                                         \
    __syncthreads();                                                          \
  } while (0)

  for (int g = 0; g < 8; ++g) {
    G2_STEP(g, 0, true, g, 128, 1);            // compute (g, k-lo); load (g, k-hi)
    if (g < 7) {
      G2_STEP(g, 1, true, g + 1, 0, 0);        // compute (g, k-hi); load (g+1, k-lo)
    } else {
      G2_STEP(7, 1, false, 0, 0, 0);           // last: no further issue
    }
  }

#undef G2_STEP
#undef G2_ISSUE
}

// ---------------------------------------------------------------------------
extern "C" void kernel_launch(void* const* d_in, const int* in_sizes, int n_in,
                              void* d_out, int out_size, void* d_ws, size_t ws_size,
                              hipStream_t stream) {
  const float* in1 = (const float*)d_in[0];
  const float* in2 = (const float*)d_in[1];
  const float* w1  = (const float*)d_in[2];
  const float* w2  = (const float*)d_in[3];
  float* out = (float*)d_out;

  char* ws = (char*)d_ws;
  bf16_t* in2b = (bf16_t*)(ws);                                   // 16 MiB
  bf16_t* w1t  = (bf16_t*)(ws + (16u << 20));                     // 256 KiB
  float*  lin  = (float*) (ws + (16u << 20) + (256u << 10));      // 512 KiB
  bf16_t* T    = (bf16_t*)(ws + (17u << 20));                     // 32 MiB

  prep2_kernel<<<8256, 256, 0, stream>>>(in2, w1, w2, in2b, w1t, lin);
  gemm1_kernel<<<512, 256, 0, stream>>>(in1, w1t, w2, T, lin);
  gemm2_kernel<<<512, 256, 0, stream>>>(T, in2b, lin, out);
}

// Round 9
// 150.839 us; speedup vs baseline: 1.1619x; 1.1619x over previous
//
#include <hip/hip_runtime.h>
#include <hip/hip_bf16.h>
#include <cstdint>
#include <cstddef>

// ---------------------------------------------------------------------------
// Biaffine: out[b,x,y,o] = sum_ij in1[b,x,i] w1[i,o,j] in2[b,y,j] + lin terms
// B=32 S=1024 D=256 O=2.
//   prep : cast inputs to bf16, lin terms, w1 transpose          (R4 version)
//   gemm1: T[bx, oj] = in1b @ w1t^T      (16x16x32, BM=64)       (R4 version)
//   gemm2: R4 structure (A in registers, 32x32x16, 2-slot 16 KB dbuf,
//          __syncthreads, 2 blocks/CU) + ONE change: lin staged in LDS so the
//          epilogue has zero global loads (no forced store-drains mid-burst).
// ---------------------------------------------------------------------------

typedef __bf16 bf16_t;
typedef __bf16 bf16x4 __attribute__((ext_vector_type(4)));
typedef __bf16 bf16x8 __attribute__((ext_vector_type(8)));
typedef float  f32x4  __attribute__((ext_vector_type(4)));
typedef float  f32x16 __attribute__((ext_vector_type(16)));

#define NB   32
#define NS   1024
#define ND   256
#define NM   (NB * NS)
#define NN1  512

__device__ __forceinline__ void gload_lds16(const void* g, void* l) {
  __builtin_amdgcn_global_load_lds(
      (__attribute__((address_space(1))) void*)g,
      (__attribute__((address_space(3))) void*)l, 16, 0, 0);
}

// ---------------------------------------------------------------------------
// prep (R4 version)
// ---------------------------------------------------------------------------
__global__ __launch_bounds__(256) void prep_kernel(
    const float* __restrict__ in1, const float* __restrict__ in2,
    const float* __restrict__ w1,  const float* __restrict__ w2,
    bf16_t* __restrict__ in1b, bf16_t* __restrict__ in2b,
    bf16_t* __restrict__ w1t,  float* __restrict__ lin)
{
  int bid = blockIdx.x;
  if (bid < 16384) {
    int wave = threadIdx.x >> 6;
    int lane = threadIdx.x & 63;
    int r  = bid * 4 + wave;
    int is2 = (r >= NM) ? 1 : 0;
    int lr = r & (NM - 1);
    const float* src = is2 ? in2 : in1;
    bf16_t*      dst = is2 ? in2b : in1b;

    float4 v = *(const float4*)(src + (size_t)lr * ND + lane * 4);
    bf16x4 h;
    h[0] = (bf16_t)v.x; h[1] = (bf16_t)v.y; h[2] = (bf16_t)v.z; h[3] = (bf16_t)v.w;
    *(bf16x4*)(dst + (size_t)lr * ND + lane * 4) = h;

    int dbase = is2 * ND + lane * 4;
    float a0 = v.x * w2[(dbase + 0) * 2 + 0] + v.y * w2[(dbase + 1) * 2 + 0]
             + v.z * w2[(dbase + 2) * 2 + 0] + v.w * w2[(dbase + 3) * 2 + 0];
    float a1 = v.x * w2[(dbase + 0) * 2 + 1] + v.y * w2[(dbase + 1) * 2 + 1]
             + v.z * w2[(dbase + 2) * 2 + 1] + v.w * w2[(dbase + 3) * 2 + 1];
    #pragma unroll
    for (int off = 32; off > 0; off >>= 1) {
      a0 += __shfl_down(a0, off, 64);
      a1 += __shfl_down(a1, off, 64);
    }
    if (lane == 0) {
      if (is2) { a0 += w2[2 * ND * 2 + 0]; a1 += w2[2 * ND * 2 + 1]; }
      lin[r * 2 + 0] = a0;
      lin[r * 2 + 1] = a1;
    }
  } else {
    int wb = bid - 16384;
    int t  = threadIdx.x;
    #pragma unroll
    for (int e = 0; e < 8; ++e) {
      int q  = wb * 2048 + e * 256 + t;
      int oj = q >> 8;
      int i  = q & 255;
      w1t[q] = (bf16_t)w1[i * NN1 + oj];
    }
  }
}

// ---------------------------------------------------------------------------
// gemm1 (R4 version): T[m,oj] = in1b[m,:] . w1t[oj,:]
// ---------------------------------------------------------------------------
__global__ __launch_bounds__(256, 3) void gemm1_kernel(
    const bf16_t* __restrict__ A, const bf16_t* __restrict__ Bt,
    bf16_t* __restrict__ T)
{
  __shared__ __align__(16) bf16_t Ap[64 * 256];
  __shared__ __align__(16) bf16_t Bc[2][128 * 32];

  int m0 = blockIdx.x * 64;
  int t = threadIdx.x, lane = t & 63, wid = t >> 6;
  int wm = (wid >> 1) * 32, wn = (wid & 1) * 64;

  #pragma unroll
  for (int i = 0; i < 8; ++i) {
    int unit = i * 256 + t;
    int row = unit >> 5;
    int c   = unit & 31;
    int cs  = c ^ (row & 7);
    gload_lds16(A + (size_t)(m0 + row) * ND + cs * 8, (char*)Ap + unit * 16);
  }
  #pragma unroll
  for (int i = 0; i < 2; ++i) {
    int unit = i * 256 + t;
    int row = unit >> 2, c = unit & 3, cs = c ^ (row & 3);
    gload_lds16(Bt + (size_t)row * ND + cs * 8, (char*)Bc[0] + unit * 16);
  }
  __syncthreads();

  f32x4 acc[2][4] = {};

  for (int s = 0; s < 32; ++s) {
    if (s + 1 < 32) {
      int nt = (s + 1) >> 3, j0 = ((s + 1) & 7) * 32;
      bf16_t* dst = (bf16_t*)Bc[(s + 1) & 1];
      #pragma unroll
      for (int i = 0; i < 2; ++i) {
        int unit = i * 256 + t;
        int row = unit >> 2, c = unit & 3, cs = c ^ (row & 3);
        gload_lds16(Bt + (size_t)(nt * 128 + row) * ND + j0 + cs * 8,
                    (char*)dst + unit * 16);
      }
    }
    const bf16_t* Bcur = Bc[s & 1];
    bf16x8 bfr[4];
    #pragma unroll
    for (int ni = 0; ni < 4; ++ni) {
      int r = wn + ni * 16 + (lane & 15);
      int cp = (lane >> 4) ^ (r & 3);
      bfr[ni] = *(const bf16x8*)&Bcur[r * 32 + cp * 8];
    }
    #pragma unroll
    for (int mi = 0; mi < 2; ++mi) {
      int r = wm + mi * 16 + (lane & 15);
      int cl = (s & 7) * 4 + (lane >> 4);
      int cp = cl ^ (r & 7);
      bf16x8 af = *(const bf16x8*)&Ap[r * 256 + cp * 8];
      #pragma unroll
      for (int ni = 0; ni < 4; ++ni)
        acc[mi][ni] = __builtin_amdgcn_mfma_f32_16x16x32_bf16(
            af, bfr[ni], acc[mi][ni], 0, 0, 0);
    }
    if ((s & 7) == 7) {
      int nt = s >> 3;
      #pragma unroll
      for (int mi = 0; mi < 2; ++mi) {
        int row = m0 + wm + mi * 16 + ((lane >> 4) << 2);
        #pragma unroll
        for (int ni = 0; ni < 4; ++ni) {
          int col = nt * 128 + wn + ni * 16 + (lane & 15);
          #pragma unroll
          for (int r_ = 0; r_ < 4; ++r_)
            T[(size_t)(row + r_) * NN1 + col] = (bf16_t)acc[mi][ni][r_];
          acc[mi][ni] = (f32x4){0.f, 0.f, 0.f, 0.f};
        }
      }
    }
    __syncthreads();
  }
}

// ---------------------------------------------------------------------------
// gemm2 (R4 structure + lin-in-LDS): per (b, 64-row x-tile). A = T rows in
// registers (af[2][16] = 128 VGPR). B streamed [128y x 64k] 16 KB chunks,
// 2-slot dbuf (union with one-shot A staging). 32 steps = 8 y-tiles x 4 kc.
// lin1/lin2 staged in LDS once -> epilogue is ds_read + stores only.
// ---------------------------------------------------------------------------
__global__ __launch_bounds__(256, 2) void gemm2_kernel(
    const bf16_t* __restrict__ Tm, const bf16_t* __restrict__ in2b,
    const float* __restrict__ lin, float* __restrict__ out)
{
  // 64 KB (A-stage union / 2x16 KB ring) + 512 B lin1 + 8 KB lin2
  __shared__ __align__(16) char smem[65536 + 512 + 8192];
  bf16_t* Bbuf[2] = { (bf16_t*)smem, (bf16_t*)(smem + 16384) };

  // XCD-aware bijective swizzle: 512 blocks, 64/XCD -> 4 batches per XCD
  int blk = (blockIdx.x & 7) * 64 + (blockIdx.x >> 3);
  int b   = blk >> 4;
  int x0  = (blk & 15) * 64;
  const bf16_t* Tb = Tm   + (size_t)b * NS * NN1;
  const bf16_t* Ib = in2b + (size_t)b * NS * ND;

  int t = threadIdx.x, lane = t & 63, wid = t >> 6;
  int wx = (wid >> 1) * 32;        // x-slot: 0 or 32
  int wy = (wid & 1) * 64;         // y-slot within 128-wide y-tile: 0 or 64
  int l31 = lane & 31, lhi = lane >> 5;

  // ---- stage A-panel 64x512 (swizzled) + lin into LDS, one burst ----
  bf16_t* Ap = (bf16_t*)smem;
  #pragma unroll
  for (int i = 0; i < 16; ++i) {
    int unit = i * 256 + t;
    int row = unit >> 6;
    int c   = unit & 63;
    int cs  = c ^ (row & 7);
    gload_lds16(Tb + (size_t)(x0 + row) * NN1 + cs * 8, (char*)Ap + unit * 16);
  }
  if (t < 32)
    gload_lds16(lin + ((size_t)b * NS + x0) * 2 + t * 4, smem + 65536 + t * 16);
  #pragma unroll
  for (int i = 0; i < 2; ++i) {
    int u = i * 256 + t;
    gload_lds16(lin + ((size_t)NM + (size_t)b * NS) * 2 + u * 4,
                smem + 66048 + u * 16);
  }
  __syncthreads();

  // ---- prefill A-frags: af[o][ks], 32x bf16x8 = 128 VGPR ----
  bf16x8 af[2][16];
  {
    int row = wx + l31;
    #pragma unroll
    for (int o = 0; o < 2; ++o)
      #pragma unroll
      for (int ks = 0; ks < 16; ++ks) {
        int ls = o * 32 + ks * 2 + lhi;
        int sm = ls ^ (row & 7);
        af[o][ks] = *(const bf16x8*)&Ap[(row * 64 + sm) * 8];
      }
  }
  __syncthreads();   // Ap dead; ring may overwrite (lin region is separate)

  // ---- stage B chunk 0 (yi=0,kc=0): 1024 units, 8 slots/row, ^row&7 ----
  #pragma unroll
  for (int i = 0; i < 4; ++i) {
    int u = i * 256 + t;
    int row = u >> 3, sm = u & 7;
    int cs = sm ^ (row & 7);
    gload_lds16(Ib + (size_t)row * ND + cs * 8, (char*)Bbuf[0] + u * 16);
  }
  __syncthreads();

  f32x16 acc[2][2] = {};   // [ni][o]
  float2* outb = (float2*)(out + (size_t)b * NS * NS * 2);
  const float2* l1s = (const float2*)(smem + 65536);
  const float2* l2s = (const float2*)(smem + 66048);
  int lrow_base = wx + 4 * lhi;

  for (int yi = 0; yi < 8; ++yi) {
    #pragma unroll
    for (int kc = 0; kc < 4; ++kc) {
      // prefetch next chunk (parity (kc+1)&1 is compile-time)
      if (yi < 7 || kc < 3) {
        int c1 = yi * 4 + kc + 1;
        int yn = c1 >> 2, kn = (c1 & 3) * 64;
        char* dst = (char*)Bbuf[(kc + 1) & 1];
        #pragma unroll
        for (int i = 0; i < 4; ++i) {
          int u = i * 256 + t;
          int row = u >> 3, sm = u & 7;
          int cs = sm ^ (row & 7);
          gload_lds16(Ib + (size_t)(yn * 128 + row) * ND + kn + cs * 8,
                      dst + u * 16);
        }
      }
      const bf16_t* Bp = Bbuf[kc & 1];
      #pragma unroll
      for (int ni = 0; ni < 2; ++ni) {
        int row = wy + ni * 32 + l31;
        #pragma unroll
        for (int k2 = 0; k2 < 4; ++k2) {
          int ls = k2 * 2 + lhi;
          int sm = ls ^ (row & 7);
          bf16x8 bf = *(const bf16x8*)&Bp[(row * 8 + sm) * 8];
          acc[ni][0] = __builtin_amdgcn_mfma_f32_32x32x16_bf16(
              af[0][kc * 4 + k2], bf, acc[ni][0], 0, 0, 0);
          acc[ni][1] = __builtin_amdgcn_mfma_f32_32x32x16_bf16(
              af[1][kc * 4 + k2], bf, acc[ni][1], 0, 0, 0);
        }
      }
      if (kc == 3) {
        // epilogue: LDS-only lin reads + float2 stores
        int y0 = yi * 128;
        float2 l2[2];
        #pragma unroll
        for (int ni = 0; ni < 2; ++ni) l2[ni] = l2s[y0 + wy + ni * 32 + l31];
        #pragma unroll
        for (int r = 0; r < 16; ++r) {
          int lrow = lrow_base + (r & 3) + 8 * (r >> 2);
          float2 l1 = l1s[lrow];
          int row = x0 + lrow;
          #pragma unroll
          for (int ni = 0; ni < 2; ++ni) {
            int col = y0 + wy + ni * 32 + l31;
            float2 v;
            v.x = acc[ni][0][r] + l1.x + l2[ni].x;
            v.y = acc[ni][1][r] + l1.y + l2[ni].y;
            outb[(size_t)row * NS + col] = v;
          }
        }
        acc[0][0] = (f32x16)(0.f); acc[0][1] = (f32x16)(0.f);
        acc[1][0] = (f32x16)(0.f); acc[1][1] = (f32x16)(0.f);
      }
      __syncthreads();
    }
  }
}

// ---------------------------------------------------------------------------
extern "C" void kernel_launch(void* const* d_in, const int* in_sizes, int n_in,
                              void* d_out, int out_size, void* d_ws, size_t ws_size,
                              hipStream_t stream) {
  const float* in1 = (const float*)d_in[0];
  const float* in2 = (const float*)d_in[1];
  const float* w1  = (const float*)d_in[2];
  const float* w2  = (const float*)d_in[3];
  float* out = (float*)d_out;

  char* ws = (char*)d_ws;
  bf16_t* in1b = (bf16_t*)(ws);                                   // 16 MiB
  bf16_t* in2b = (bf16_t*)(ws + (16u << 20));                     // 16 MiB
  bf16_t* w1t  = (bf16_t*)(ws + (32u << 20));                     // 256 KiB
  float*  lin  = (float*) (ws + (32u << 20) + (256u << 10));      // 512 KiB
  bf16_t* T    = (bf16_t*)(ws + (33u << 20));                     // 32 MiB

  prep_kernel<<<16448, 256, 0, stream>>>(in1, in2, w1, w2, in1b, in2b, w1t, lin);
  gemm1_kernel<<<512, 256, 0, stream>>>(in1b, w1t, T);
  gemm2_kernel<<<512, 256, 0, stream>>>(T, in2b, lin, out);
}